// Round 2
// baseline (821.999 us; speedup 1.0000x reference)
//
#include <hip/hip_runtime.h>
#include <math.h>

#define RAD_N 9
#define ELE_N 40
#define AZI_N 80
#define M_TOT 28800          // RAD_N*ELE_N*AZI_N
#define NPTS 1024
#define NSAMP 30
#define BATCH 2
#define VOX_R2 0.09f
#define EPSBN 1e-5f

// ---------------------------------------------------------------------------
// Kernel 1: neighbor scan + raise-to-16ch, per-(b,m,ch) max/min + BN0 stats
// grid = (ceil(M/256), B), block = 256
__global__ __launch_bounds__(256)
void k_neighbor(const float* __restrict__ pts,
                const float* __restrict__ w_raise,
                const float* __restrict__ b_raise,
                float* __restrict__ xmax, float* __restrict__ xmin,
                float* __restrict__ stats0)
{
    __shared__ float dl[NPTS * 3];
    const int b = blockIdx.y;
    const float* P = pts + (size_t)b * NPTS * 3;
    const float cx = P[(NPTS - 1) * 3 + 0];
    const float cy = P[(NPTS - 1) * 3 + 1];
    const float cz = P[(NPTS - 1) * 3 + 2];
    for (int n = threadIdx.x; n < NPTS; n += 256) {
        dl[n * 3 + 0] = P[n * 3 + 0] - cx;
        dl[n * 3 + 1] = P[n * 3 + 1] - cy;
        dl[n * 3 + 2] = P[n * 3 + 2] - cz;
    }
    __syncthreads();

    float wr0[16], wr1[16], wr2[16], br[16];
#pragma unroll
    for (int ch = 0; ch < 16; ch++) {
        wr0[ch] = w_raise[ch * 3 + 0];
        wr1[ch] = w_raise[ch * 3 + 1];
        wr2[ch] = w_raise[ch * 3 + 2];
        br[ch]  = b_raise[ch];
    }

    float mx[16], mn[16], sm[16], sq[16];
#pragma unroll
    for (int ch = 0; ch < 16; ch++) { mx[ch] = -1e30f; mn[ch] = 1e30f; sm[ch] = 0.f; sq[ch] = 0.f; }

    const int m = blockIdx.x * 256 + threadIdx.x;
    if (m < M_TOT) {
        const int ri = m / (ELE_N * AZI_N);
        const int rm = m - ri * (ELE_N * AZI_N);
        const int ei = rm / AZI_N;
        const int ai = rm - ei * AZI_N;
        // voxel center in double to match numpy f64->f32
        const double rd = (ri + 0.5) * (2.0 / (double)RAD_N);
        const double ed = (ei + 0.5) * (M_PI / (double)ELE_N);
        const double ad = (ai + 0.5) * (2.0 * M_PI / (double)AZI_N);
        const float vx = (float)(rd * sin(ed) * cos(ad));
        const float vy = (float)(rd * sin(ed) * sin(ad));
        const float vz = (float)(rd * cos(ed));
        const float vv = vx * vx + vy * vy + vz * vz;
        const float ang = -((float)ai * (float)(2.0 * M_PI / (double)AZI_N));
        const float cA = cosf(ang), sA = sinf(ang);

        int cnt = 0;
        for (int n = 0; n < NPTS && cnt < NSAMP; n++) {
            const float dx = dl[n * 3 + 0];
            const float dy = dl[n * 3 + 1];
            const float dz = dl[n * 3 + 2];
            const float dn2 = dx * dx + dy * dy + dz * dz;
            const float dot = dx * vx + dy * vy + dz * vz;
            const float d2 = dn2 + vv - 2.f * dot;
            if (d2 <= VOX_R2) {
                cnt++;
                const float rx = dx - vx, ry = dy - vy, rz = dz - vz;
                const float ox =  rx * cA + ry * sA;
                const float oy = -rx * sA + ry * cA;
                const float oz = rz;
#pragma unroll
                for (int ch = 0; ch < 16; ch++) {
                    const float x = wr0[ch] * ox + wr1[ch] * oy + wr2[ch] * oz + br[ch];
                    mx[ch] = fmaxf(mx[ch], x);
                    mn[ch] = fminf(mn[ch], x);
                    sm[ch] += x;
                    sq[ch] += x * x;
                }
            }
        }
        const int rem = NSAMP - cnt;
        if (rem > 0) {
            const float fr = (float)rem;
#pragma unroll
            for (int ch = 0; ch < 16; ch++) {
                const float x = br[ch];
                mx[ch] = fmaxf(mx[ch], x);
                mn[ch] = fminf(mn[ch], x);
                sm[ch] += fr * x;
                sq[ch] += fr * x * x;
            }
        }
#pragma unroll
        for (int ch = 0; ch < 16; ch++) {
            xmax[((size_t)b * 16 + ch) * M_TOT + m] = mx[ch];
            xmin[((size_t)b * 16 + ch) * M_TOT + m] = mn[ch];
        }
    }

    // block-level stats reduction: wave shfl -> LDS -> 2 atomics per channel
    __shared__ float red[4][32];
    const int wv = threadIdx.x >> 6;
    const int ln = threadIdx.x & 63;
#pragma unroll
    for (int ch = 0; ch < 16; ch++) {
        float s = sm[ch], q = sq[ch];
        for (int off = 32; off; off >>= 1) {
            s += __shfl_xor(s, off);
            q += __shfl_xor(q, off);
        }
        if (ln == 0) { red[wv][ch] = s; red[wv][16 + ch] = q; }
    }
    __syncthreads();
    if (threadIdx.x < 32) {
        const float v = red[0][threadIdx.x] + red[1][threadIdx.x] +
                        red[2][threadIdx.x] + red[3][threadIdx.x];
        const int dst = (threadIdx.x < 16) ? threadIdx.x : (16 + threadIdx.x); // sum[ch] / sumsq at +32
        atomicAdd(&stats0[dst], v);
    }
}

// ---------------------------------------------------------------------------
// Kernel 2: BN0 affine + relu applied to the max/min -> act0 (B,16,9,40,80)
__global__ __launch_bounds__(256)
void k_bn0(const float* __restrict__ xmax, const float* __restrict__ xmin,
           float* __restrict__ act,
           const float* __restrict__ stats,
           const float* __restrict__ g, const float* __restrict__ be)
{
    const int idx = blockIdx.x * 256 + threadIdx.x;
    const int total = BATCH * 16 * M_TOT;
    if (idx >= total) return;
    const int ch = (idx / M_TOT) & 15;
    const float cnt = (float)((size_t)BATCH * M_TOT * NSAMP);
    const float mean = stats[ch] / cnt;
    const float var  = stats[32 + ch] / cnt - mean * mean;
    const float sc = g[ch] * rsqrtf(var + EPSBN);
    const float sh = be[ch] - mean * sc;
    const float v = (sc >= 0.f) ? xmax[idx] : xmin[idx];
    const float r = sc * v + sh;
    act[idx] = r > 0.f ? r : 0.f;
}

// ---------------------------------------------------------------------------
// Conv 3x3x3, H zero-pad, W wrap, D valid. block=320 (4 rows x 80), one (b,co,d) per block.
// grid = (10, DOUT, B*32)
template <int CIN, int DOUT>
__global__ __launch_bounds__(320)
void k_conv(const float* __restrict__ xin, const float* __restrict__ wgt,
            const float* __restrict__ bias,
            float* __restrict__ y, float* __restrict__ stats)
{
    constexpr int DIN = DOUT + 2;
    __shared__ float lw[CIN * 27];
    const int co = blockIdx.z & 31;
    const int b  = blockIdx.z >> 5;
    const int d  = blockIdx.y;
    for (int i = threadIdx.x; i < CIN * 27; i += 320) lw[i] = wgt[co * CIN * 27 + i];
    __syncthreads();

    const int h = blockIdx.x * 4 + threadIdx.x / 80;
    const int w = threadIdx.x % 80;
    const int wm1 = (w == 0) ? 79 : w - 1;
    const int wp1 = (w == 79) ? 0 : w + 1;

    float acc = bias[co];
    const float* xb = xin + (size_t)b * CIN * DIN * 3200;
#pragma unroll 1
    for (int ci = 0; ci < CIN; ci++) {
        const float* xc = xb + ((size_t)ci * DIN + d) * 3200;
        const float* lwc = lw + ci * 27;
#pragma unroll
        for (int kd = 0; kd < 3; kd++) {
            const float* xd = xc + kd * 3200;
#pragma unroll
            for (int kh = 0; kh < 3; kh++) {
                const int hh = h + kh - 1;
                if (hh < 0 || hh >= ELE_N) continue;
                const float* xr = xd + hh * 80;
                acc = fmaf(xr[wm1], lwc[kd * 9 + kh * 3 + 0], acc);
                acc = fmaf(xr[w],   lwc[kd * 9 + kh * 3 + 1], acc);
                acc = fmaf(xr[wp1], lwc[kd * 9 + kh * 3 + 2], acc);
            }
        }
    }
    y[(((size_t)b * 32 + co) * DOUT + d) * 3200 + h * 80 + w] = acc;

    // stats (all threads in block share co)
    float s = acc, q = acc * acc;
    for (int off = 32; off; off >>= 1) {
        s += __shfl_xor(s, off);
        q += __shfl_xor(q, off);
    }
    __shared__ float red[5][2];
    const int wv = threadIdx.x >> 6;
    if ((threadIdx.x & 63) == 0) { red[wv][0] = s; red[wv][1] = q; }
    __syncthreads();
    if (threadIdx.x == 0) {
        float S = 0.f, Q = 0.f;
#pragma unroll
        for (int i = 0; i < 5; i++) { S += red[i][0]; Q += red[i][1]; }
        atomicAdd(&stats[co], S);
        atomicAdd(&stats[32 + co], Q);
    }
}

// ---------------------------------------------------------------------------
// BN + relu on a conv raw output (32 channels), layout (B,32,dhw)
__global__ __launch_bounds__(256)
void k_bnrelu(const float* __restrict__ y, float* __restrict__ act,
              const float* __restrict__ stats,
              const float* __restrict__ g, const float* __restrict__ be,
              float per_ch_count, int dhw, int total)
{
    const int idx = blockIdx.x * 256 + threadIdx.x;
    if (idx >= total) return;
    const int ch = (idx / dhw) & 31;
    const float mean = stats[ch] / per_ch_count;
    const float var  = stats[32 + ch] / per_ch_count - mean * mean;
    const float sc = g[ch] * rsqrtf(var + EPSBN);
    const float sh = be[ch] - mean * sc;
    const float r = sc * y[idx] + sh;
    act[idx] = r > 0.f ? r : 0.f;
}

// ---------------------------------------------------------------------------
// Final: max over H,W of relu(bn(y4)), y4 (B,32,1,40,80). grid=64 blocks (b*32+co)
__global__ __launch_bounds__(256)
void k_final(const float* __restrict__ y4,
             const float* __restrict__ stats,
             const float* __restrict__ g, const float* __restrict__ be,
             float* __restrict__ out)
{
    const int b = blockIdx.x >> 5;
    const int co = blockIdx.x & 31;
    const float* src = y4 + ((size_t)b * 32 + co) * 3200;
    float mx = -1e30f, mn = 1e30f;
    for (int i = threadIdx.x; i < 3200; i += 256) {
        const float v = src[i];
        mx = fmaxf(mx, v);
        mn = fminf(mn, v);
    }
    for (int off = 32; off; off >>= 1) {
        mx = fmaxf(mx, __shfl_xor(mx, off));
        mn = fminf(mn, __shfl_xor(mn, off));
    }
    __shared__ float rmx[4], rmn[4];
    const int wv = threadIdx.x >> 6;
    if ((threadIdx.x & 63) == 0) { rmx[wv] = mx; rmn[wv] = mn; }
    __syncthreads();
    if (threadIdx.x == 0) {
        float MX = rmx[0], MN = rmn[0];
#pragma unroll
        for (int i = 1; i < 4; i++) { MX = fmaxf(MX, rmx[i]); MN = fminf(MN, rmn[i]); }
        const float cnt = (float)(BATCH * 1 * 3200);
        const float mean = stats[co] / cnt;
        const float var  = stats[32 + co] / cnt - mean * mean;
        const float sc = g[co] * rsqrtf(var + EPSBN);
        const float sh = be[co] - mean * sc;
        const float v = (sc >= 0.f) ? MX : MN;
        const float r = sc * v + sh;
        out[b * 32 + co] = r > 0.f ? r : 0.f;
    }
}

// ---------------------------------------------------------------------------
extern "C" void kernel_launch(void* const* d_in, const int* in_sizes, int n_in,
                              void* d_out, int out_size, void* d_ws, size_t ws_size,
                              hipStream_t stream)
{
    const float* pts     = (const float*)d_in[0];
    const float* w_raise = (const float*)d_in[1];
    const float* b_raise = (const float*)d_in[2];
    const float* g0      = (const float*)d_in[3];
    const float* be0     = (const float*)d_in[4];
    const float* w1  = (const float*)d_in[5];
    const float* b1  = (const float*)d_in[6];
    const float* g1  = (const float*)d_in[7];
    const float* be1 = (const float*)d_in[8];
    const float* w2  = (const float*)d_in[9];
    const float* b2  = (const float*)d_in[10];
    const float* g2  = (const float*)d_in[11];
    const float* be2 = (const float*)d_in[12];
    const float* w3  = (const float*)d_in[13];
    const float* b3  = (const float*)d_in[14];
    const float* g3  = (const float*)d_in[15];
    const float* be3 = (const float*)d_in[16];
    const float* w4  = (const float*)d_in[17];
    const float* b4  = (const float*)d_in[18];
    const float* g4  = (const float*)d_in[19];
    const float* be4 = (const float*)d_in[20];
    float* out = (float*)d_out;

    // workspace layout (floats), with reuse:
    //   stats: 5*64 (rounded to 512)
    //   act0 : B*16*M = 921600
    //   P    : 1433600  (xmax, later conv raw y)
    //   Q    : 1433600  (xmin, later activated input)
    float* wsf   = (float*)d_ws;
    float* stats = wsf;                 // 512 floats
    float* act0  = wsf + 512;
    float* P     = act0 + (size_t)BATCH * 16 * M_TOT;   // 921600
    float* Q     = P + 1433600;
    float* xmax = P, *xmin = Q;
    float* Y = P, *A = Q;

    hipMemsetAsync(stats, 0, 512 * sizeof(float), stream);

    k_neighbor<<<dim3((M_TOT + 255) / 256, BATCH), 256, 0, stream>>>(
        pts, w_raise, b_raise, xmax, xmin, stats);

    {
        const int total = BATCH * 16 * M_TOT;
        k_bn0<<<(total + 255) / 256, 256, 0, stream>>>(xmax, xmin, act0, stats, g0, be0);
    }

    // layer1: act0 (B,16,9,...) -> Y (B,32,7,...)
    k_conv<16, 7><<<dim3(10, 7, BATCH * 32), 320, 0, stream>>>(act0, w1, b1, Y, stats + 64);
    k_bnrelu<<<(BATCH * 32 * 7 * 3200 + 255) / 256, 256, 0, stream>>>(
        Y, A, stats + 64, g1, be1, (float)(BATCH * 7 * 3200), 7 * 3200, BATCH * 32 * 7 * 3200);

    // layer2: A (B,32,7) -> Y (B,32,5)
    k_conv<32, 5><<<dim3(10, 5, BATCH * 32), 320, 0, stream>>>(A, w2, b2, Y, stats + 128);
    k_bnrelu<<<(BATCH * 32 * 5 * 3200 + 255) / 256, 256, 0, stream>>>(
        Y, A, stats + 128, g2, be2, (float)(BATCH * 5 * 3200), 5 * 3200, BATCH * 32 * 5 * 3200);

    // layer3: A (B,32,5) -> Y (B,32,3)
    k_conv<32, 3><<<dim3(10, 3, BATCH * 32), 320, 0, stream>>>(A, w3, b3, Y, stats + 192);
    k_bnrelu<<<(BATCH * 32 * 3 * 3200 + 255) / 256, 256, 0, stream>>>(
        Y, A, stats + 192, g3, be3, (float)(BATCH * 3 * 3200), 3 * 3200, BATCH * 32 * 3 * 3200);

    // layer4: A (B,32,3) -> Y (B,32,1)
    k_conv<32, 1><<<dim3(10, 1, BATCH * 32), 320, 0, stream>>>(A, w4, b4, Y, stats + 256);

    k_final<<<BATCH * 32, 256, 0, stream>>>(Y, stats + 256, g4, be4, out);
}

// Round 3
// 585.908 us; speedup vs baseline: 1.4029x; 1.4029x over previous
//
#include <hip/hip_runtime.h>
#include <math.h>

#define RAD_N 9
#define ELE_N 40
#define AZI_N 80
#define M_TOT 28800          // RAD_N*ELE_N*AZI_N
#define NPTS 1024
#define NSAMP 30
#define BATCH 2
#define VOX_R2 0.09f
#define EPSBN 1e-5f

// ---------------------------------------------------------------------------
// Kernel 1: neighbor scan + raise-to-16ch, per-(b,m,ch) max/min + BN0 stats
// grid = (ceil(M/256), B), block = 256
__global__ __launch_bounds__(256)
void k_neighbor(const float* __restrict__ pts,
                const float* __restrict__ w_raise,
                const float* __restrict__ b_raise,
                float* __restrict__ xmax, float* __restrict__ xmin,
                float* __restrict__ stats0)
{
    __shared__ float dl[NPTS * 3];
    const int b = blockIdx.y;
    const float* P = pts + (size_t)b * NPTS * 3;
    const float cx = P[(NPTS - 1) * 3 + 0];
    const float cy = P[(NPTS - 1) * 3 + 1];
    const float cz = P[(NPTS - 1) * 3 + 2];
    for (int n = threadIdx.x; n < NPTS; n += 256) {
        dl[n * 3 + 0] = P[n * 3 + 0] - cx;
        dl[n * 3 + 1] = P[n * 3 + 1] - cy;
        dl[n * 3 + 2] = P[n * 3 + 2] - cz;
    }
    __syncthreads();

    float wr0[16], wr1[16], wr2[16], br[16];
#pragma unroll
    for (int ch = 0; ch < 16; ch++) {
        wr0[ch] = w_raise[ch * 3 + 0];
        wr1[ch] = w_raise[ch * 3 + 1];
        wr2[ch] = w_raise[ch * 3 + 2];
        br[ch]  = b_raise[ch];
    }

    float mx[16], mn[16], sm[16], sq[16];
#pragma unroll
    for (int ch = 0; ch < 16; ch++) { mx[ch] = -1e30f; mn[ch] = 1e30f; sm[ch] = 0.f; sq[ch] = 0.f; }

    const int m = blockIdx.x * 256 + threadIdx.x;
    if (m < M_TOT) {
        const int ri = m / (ELE_N * AZI_N);
        const int rm = m - ri * (ELE_N * AZI_N);
        const int ei = rm / AZI_N;
        const int ai = rm - ei * AZI_N;
        // voxel center in double to match numpy f64->f32
        const double rd = (ri + 0.5) * (2.0 / (double)RAD_N);
        const double ed = (ei + 0.5) * (M_PI / (double)ELE_N);
        const double ad = (ai + 0.5) * (2.0 * M_PI / (double)AZI_N);
        const float vx = (float)(rd * sin(ed) * cos(ad));
        const float vy = (float)(rd * sin(ed) * sin(ad));
        const float vz = (float)(rd * cos(ed));
        const float vv = vx * vx + vy * vy + vz * vz;
        const float ang = -((float)ai * (float)(2.0 * M_PI / (double)AZI_N));
        const float cA = cosf(ang), sA = sinf(ang);

        int cnt = 0;
        for (int n = 0; n < NPTS && cnt < NSAMP; n++) {
            const float dx = dl[n * 3 + 0];
            const float dy = dl[n * 3 + 1];
            const float dz = dl[n * 3 + 2];
            const float dn2 = dx * dx + dy * dy + dz * dz;
            const float dot = dx * vx + dy * vy + dz * vz;
            const float d2 = dn2 + vv - 2.f * dot;
            if (d2 <= VOX_R2) {
                cnt++;
                const float rx = dx - vx, ry = dy - vy, rz = dz - vz;
                const float ox =  rx * cA + ry * sA;
                const float oy = -rx * sA + ry * cA;
                const float oz = rz;
#pragma unroll
                for (int ch = 0; ch < 16; ch++) {
                    const float x = wr0[ch] * ox + wr1[ch] * oy + wr2[ch] * oz + br[ch];
                    mx[ch] = fmaxf(mx[ch], x);
                    mn[ch] = fminf(mn[ch], x);
                    sm[ch] += x;
                    sq[ch] += x * x;
                }
            }
        }
        const int rem = NSAMP - cnt;
        if (rem > 0) {
            const float fr = (float)rem;
#pragma unroll
            for (int ch = 0; ch < 16; ch++) {
                const float x = br[ch];
                mx[ch] = fmaxf(mx[ch], x);
                mn[ch] = fminf(mn[ch], x);
                sm[ch] += fr * x;
                sq[ch] += fr * x * x;
            }
        }
#pragma unroll
        for (int ch = 0; ch < 16; ch++) {
            xmax[((size_t)b * 16 + ch) * M_TOT + m] = mx[ch];
            xmin[((size_t)b * 16 + ch) * M_TOT + m] = mn[ch];
        }
    }

    // block-level stats reduction: wave shfl -> LDS -> 2 atomics per channel
    __shared__ float red[4][32];
    const int wv = threadIdx.x >> 6;
    const int ln = threadIdx.x & 63;
#pragma unroll
    for (int ch = 0; ch < 16; ch++) {
        float s = sm[ch], q = sq[ch];
        for (int off = 32; off; off >>= 1) {
            s += __shfl_xor(s, off);
            q += __shfl_xor(q, off);
        }
        if (ln == 0) { red[wv][ch] = s; red[wv][16 + ch] = q; }
    }
    __syncthreads();
    if (threadIdx.x < 32) {
        const float v = red[0][threadIdx.x] + red[1][threadIdx.x] +
                        red[2][threadIdx.x] + red[3][threadIdx.x];
        const int dst = (threadIdx.x < 16) ? threadIdx.x : (16 + threadIdx.x); // sum[ch] / sumsq at +32
        atomicAdd(&stats0[dst], v);
    }
}

// ---------------------------------------------------------------------------
// Kernel 2: BN0 affine + relu applied to the max/min -> act0 (B,16,9,40,80)
__global__ __launch_bounds__(256)
void k_bn0(const float* __restrict__ xmax, const float* __restrict__ xmin,
           float* __restrict__ act,
           const float* __restrict__ stats,
           const float* __restrict__ g, const float* __restrict__ be)
{
    const int idx = blockIdx.x * 256 + threadIdx.x;
    const int total = BATCH * 16 * M_TOT;
    if (idx >= total) return;
    const int ch = (idx / M_TOT) & 15;
    const float cnt = (float)((size_t)BATCH * M_TOT * NSAMP);
    const float mean = stats[ch] / cnt;
    const float var  = stats[32 + ch] / cnt - mean * mean;
    const float sc = g[ch] * rsqrtf(var + EPSBN);
    const float sh = be[ch] - mean * sc;
    const float v = (sc >= 0.f) ? xmax[idx] : xmin[idx];
    const float r = sc * v + sh;
    act[idx] = r > 0.f ? r : 0.f;
}

// ---------------------------------------------------------------------------
// Conv 3x3x3, H zero-pad, W wrap, D valid.
// Each thread computes NCO=8 output channels for one (h,w); weights are read
// via wave-uniform addresses (compiler -> s_load / SGPR operands), inputs via
// L1-cached global loads: 24 FMA per 3 input loads.
// block = 320 (4 h-rows x 80 w), grid = (10, DOUT, B*4)
template <int CIN, int DOUT>
__global__ __launch_bounds__(320)
void k_conv(const float* __restrict__ xin, const float* __restrict__ wgt,
            const float* __restrict__ bias,
            float* __restrict__ y, float* __restrict__ stats)
{
    constexpr int DIN = DOUT + 2;
    const int cog = blockIdx.z & 3;          // group of 8 consecutive co
    const int b   = blockIdx.z >> 2;
    const int d   = blockIdx.y;
    const int h   = blockIdx.x * 4 + threadIdx.x / 80;
    const int w   = threadIdx.x % 80;
    const int wm1 = (w == 0) ? 79 : w - 1;
    const int wp1 = (w == 79) ? 0 : w + 1;

    float acc[8];
#pragma unroll
    for (int c = 0; c < 8; c++) acc[c] = bias[cog * 8 + c];

    const float* xb = xin + (size_t)b * CIN * DIN * 3200 + (size_t)d * 3200;
    const float* wb = wgt + (size_t)(cog * 8) * CIN * 27;

#pragma unroll 1
    for (int ci = 0; ci < CIN; ci++) {
        const float* xc  = xb + (size_t)ci * DIN * 3200;
        const float* wc  = wb + ci * 27;
#pragma unroll
        for (int kd = 0; kd < 3; kd++) {
            const float* xd = xc + kd * 3200;
#pragma unroll
            for (int kh = 0; kh < 3; kh++) {
                const int hh = h + kh - 1;
                if (hh < 0 || hh >= ELE_N) continue;
                const float* xr = xd + hh * 80;
                const float x0 = xr[wm1];
                const float x1 = xr[w];
                const float x2 = xr[wp1];
                const float* wk = wc + kd * 9 + kh * 3;
#pragma unroll
                for (int c = 0; c < 8; c++) {
                    const float* wcc = wk + c * (CIN * 27);
                    acc[c] = fmaf(x2, wcc[2], fmaf(x1, wcc[1], fmaf(x0, wcc[0], acc[c])));
                }
            }
        }
    }

#pragma unroll
    for (int c = 0; c < 8; c++) {
        y[(((size_t)b * 32 + cog * 8 + c) * DOUT + d) * 3200 + h * 80 + w] = acc[c];
    }

    // stats: per-co sum / sumsq over the block, then atomics
    __shared__ float red[5][16];
    const int wv = threadIdx.x >> 6;
    const int ln = threadIdx.x & 63;
#pragma unroll
    for (int c = 0; c < 8; c++) {
        float s = acc[c], q = acc[c] * acc[c];
        for (int off = 32; off; off >>= 1) {
            s += __shfl_xor(s, off);
            q += __shfl_xor(q, off);
        }
        if (ln == 0) { red[wv][c] = s; red[wv][8 + c] = q; }
    }
    __syncthreads();
    if (threadIdx.x < 16) {
        const float v = red[0][threadIdx.x] + red[1][threadIdx.x] + red[2][threadIdx.x] +
                        red[3][threadIdx.x] + red[4][threadIdx.x];
        const int c   = threadIdx.x & 7;
        const int isq = threadIdx.x >> 3;          // 0=sum, 1=sumsq
        atomicAdd(&stats[isq * 32 + cog * 8 + c], v);
    }
}

// ---------------------------------------------------------------------------
// BN + relu on a conv raw output (32 channels), layout (B,32,dhw)
__global__ __launch_bounds__(256)
void k_bnrelu(const float* __restrict__ y, float* __restrict__ act,
              const float* __restrict__ stats,
              const float* __restrict__ g, const float* __restrict__ be,
              float per_ch_count, int dhw, int total)
{
    const int idx = blockIdx.x * 256 + threadIdx.x;
    if (idx >= total) return;
    const int ch = (idx / dhw) & 31;
    const float mean = stats[ch] / per_ch_count;
    const float var  = stats[32 + ch] / per_ch_count - mean * mean;
    const float sc = g[ch] * rsqrtf(var + EPSBN);
    const float sh = be[ch] - mean * sc;
    const float r = sc * y[idx] + sh;
    act[idx] = r > 0.f ? r : 0.f;
}

// ---------------------------------------------------------------------------
// Final: max over H,W of relu(bn(y4)), y4 (B,32,1,40,80). grid=64 blocks (b*32+co)
__global__ __launch_bounds__(256)
void k_final(const float* __restrict__ y4,
             const float* __restrict__ stats,
             const float* __restrict__ g, const float* __restrict__ be,
             float* __restrict__ out)
{
    const int b = blockIdx.x >> 5;
    const int co = blockIdx.x & 31;
    const float* src = y4 + ((size_t)b * 32 + co) * 3200;
    float mx = -1e30f, mn = 1e30f;
    for (int i = threadIdx.x; i < 3200; i += 256) {
        const float v = src[i];
        mx = fmaxf(mx, v);
        mn = fminf(mn, v);
    }
    for (int off = 32; off; off >>= 1) {
        mx = fmaxf(mx, __shfl_xor(mx, off));
        mn = fminf(mn, __shfl_xor(mn, off));
    }
    __shared__ float rmx[4], rmn[4];
    const int wv = threadIdx.x >> 6;
    if ((threadIdx.x & 63) == 0) { rmx[wv] = mx; rmn[wv] = mn; }
    __syncthreads();
    if (threadIdx.x == 0) {
        float MX = rmx[0], MN = rmn[0];
#pragma unroll
        for (int i = 1; i < 4; i++) { MX = fmaxf(MX, rmx[i]); MN = fminf(MN, rmn[i]); }
        const float cnt = (float)(BATCH * 1 * 3200);
        const float mean = stats[co] / cnt;
        const float var  = stats[32 + co] / cnt - mean * mean;
        const float sc = g[co] * rsqrtf(var + EPSBN);
        const float sh = be[co] - mean * sc;
        const float v = (sc >= 0.f) ? MX : MN;
        const float r = sc * v + sh;
        out[b * 32 + co] = r > 0.f ? r : 0.f;
    }
}

// ---------------------------------------------------------------------------
extern "C" void kernel_launch(void* const* d_in, const int* in_sizes, int n_in,
                              void* d_out, int out_size, void* d_ws, size_t ws_size,
                              hipStream_t stream)
{
    const float* pts     = (const float*)d_in[0];
    const float* w_raise = (const float*)d_in[1];
    const float* b_raise = (const float*)d_in[2];
    const float* g0      = (const float*)d_in[3];
    const float* be0     = (const float*)d_in[4];
    const float* w1  = (const float*)d_in[5];
    const float* b1  = (const float*)d_in[6];
    const float* g1  = (const float*)d_in[7];
    const float* be1 = (const float*)d_in[8];
    const float* w2  = (const float*)d_in[9];
    const float* b2  = (const float*)d_in[10];
    const float* g2  = (const float*)d_in[11];
    const float* be2 = (const float*)d_in[12];
    const float* w3  = (const float*)d_in[13];
    const float* b3  = (const float*)d_in[14];
    const float* g3  = (const float*)d_in[15];
    const float* be3 = (const float*)d_in[16];
    const float* w4  = (const float*)d_in[17];
    const float* b4  = (const float*)d_in[18];
    const float* g4  = (const float*)d_in[19];
    const float* be4 = (const float*)d_in[20];
    float* out = (float*)d_out;

    // workspace layout (floats), with reuse:
    //   stats: 5*64 (rounded to 512)
    //   act0 : B*16*M = 921600
    //   P    : 1433600  (xmax, later conv raw y)
    //   Q    : 1433600  (xmin, later activated input)
    float* wsf   = (float*)d_ws;
    float* stats = wsf;                 // 512 floats
    float* act0  = wsf + 512;
    float* P     = act0 + (size_t)BATCH * 16 * M_TOT;   // 921600
    float* Q     = P + 1433600;
    float* xmax = P, *xmin = Q;
    float* Y = P, *A = Q;

    hipMemsetAsync(stats, 0, 512 * sizeof(float), stream);

    k_neighbor<<<dim3((M_TOT + 255) / 256, BATCH), 256, 0, stream>>>(
        pts, w_raise, b_raise, xmax, xmin, stats);

    {
        const int total = BATCH * 16 * M_TOT;
        k_bn0<<<(total + 255) / 256, 256, 0, stream>>>(xmax, xmin, act0, stats, g0, be0);
    }

    // layer1: act0 (B,16,9,...) -> Y (B,32,7,...)
    k_conv<16, 7><<<dim3(10, 7, BATCH * 4), 320, 0, stream>>>(act0, w1, b1, Y, stats + 64);
    k_bnrelu<<<(BATCH * 32 * 7 * 3200 + 255) / 256, 256, 0, stream>>>(
        Y, A, stats + 64, g1, be1, (float)(BATCH * 7 * 3200), 7 * 3200, BATCH * 32 * 7 * 3200);

    // layer2: A (B,32,7) -> Y (B,32,5)
    k_conv<32, 5><<<dim3(10, 5, BATCH * 4), 320, 0, stream>>>(A, w2, b2, Y, stats + 128);
    k_bnrelu<<<(BATCH * 32 * 5 * 3200 + 255) / 256, 256, 0, stream>>>(
        Y, A, stats + 128, g2, be2, (float)(BATCH * 5 * 3200), 5 * 3200, BATCH * 32 * 5 * 3200);

    // layer3: A (B,32,5) -> Y (B,32,3)
    k_conv<32, 3><<<dim3(10, 3, BATCH * 4), 320, 0, stream>>>(A, w3, b3, Y, stats + 192);
    k_bnrelu<<<(BATCH * 32 * 3 * 3200 + 255) / 256, 256, 0, stream>>>(
        Y, A, stats + 192, g3, be3, (float)(BATCH * 3 * 3200), 3 * 3200, BATCH * 32 * 3 * 3200);

    // layer4: A (B,32,3) -> Y (B,32,1)
    k_conv<32, 1><<<dim3(10, 1, BATCH * 4), 320, 0, stream>>>(A, w4, b4, Y, stats + 256);

    k_final<<<BATCH * 32, 256, 0, stream>>>(Y, stats + 256, g4, be4, out);
}

// Round 4
// 493.176 us; speedup vs baseline: 1.6667x; 1.1880x over previous
//
#include <hip/hip_runtime.h>
#include <math.h>

#define RAD_N 9
#define ELE_N 40
#define AZI_N 80
#define M_TOT 28800          // RAD_N*ELE_N*AZI_N
#define NPTS 1024
#define NSAMP 30
#define BATCH 2
#define VOX_R2 0.09f
#define EPSBN 1e-5f

// ---------------------------------------------------------------------------
// Kernel 0: voxel-center precompute (double precision to match numpy f64->f32)
// vox4[m] = (vx,vy,vz, |v|^2), rot2[m] = (cosA, sinA)
__global__ __launch_bounds__(256)
void k_vox(float4* __restrict__ vox4, float2* __restrict__ rot2)
{
    const int m = blockIdx.x * 256 + threadIdx.x;
    if (m >= M_TOT) return;
    const int ri = m / (ELE_N * AZI_N);
    const int rm = m - ri * (ELE_N * AZI_N);
    const int ei = rm / AZI_N;
    const int ai = rm - ei * AZI_N;
    const double rd = (ri + 0.5) * (2.0 / (double)RAD_N);
    const double ed = (ei + 0.5) * (M_PI / (double)ELE_N);
    const double ad = (ai + 0.5) * (2.0 * M_PI / (double)AZI_N);
    const float vx = (float)(rd * sin(ed) * cos(ad));
    const float vy = (float)(rd * sin(ed) * sin(ad));
    const float vz = (float)(rd * cos(ed));
    vox4[m] = make_float4(vx, vy, vz, vx * vx + vy * vy + vz * vz);
    const float ang = -((float)ai * (float)(2.0 * M_PI / (double)AZI_N));
    rot2[m] = make_float2(cosf(ang), sinf(ang));
}

// ---------------------------------------------------------------------------
// Kernel 1: wave-per-voxel ballot neighbor scan + raise-to-16ch features.
// block = 256 (4 waves = 4 voxels), grid = (M/4, B).
// Phase 1: 64 lanes test 64 points/iter; ballot+popcount-prefix appends the
//          first <=30 qualifying n (ascending) to an LDS list.
// Phase 2: lane = (sample_subgroup<<4)|ch computes x, shfl-reduce over
//          subgroups -> per-(b,m,ch) max/min/sum/sumsq.
__global__ __launch_bounds__(256)
void k_neighbor(const float* __restrict__ pts,
                const float4* __restrict__ vox4,
                const float2* __restrict__ rot2,
                const float* __restrict__ w_raise,
                const float* __restrict__ b_raise,
                float* __restrict__ xmax, float* __restrict__ xmin,
                float* __restrict__ xsum, float* __restrict__ xsq)
{
    __shared__ float4 dl4[NPTS];
    __shared__ int lists[4][NSAMP];
    const int b = blockIdx.y;
    const float* P = pts + (size_t)b * NPTS * 3;
    const float cx = P[(NPTS - 1) * 3 + 0];
    const float cy = P[(NPTS - 1) * 3 + 1];
    const float cz = P[(NPTS - 1) * 3 + 2];
    for (int n = threadIdx.x; n < NPTS; n += 256) {
        const float dx = P[n * 3 + 0] - cx;
        const float dy = P[n * 3 + 1] - cy;
        const float dz = P[n * 3 + 2] - cz;
        dl4[n] = make_float4(dx, dy, dz, dx * dx + dy * dy + dz * dz);
    }
    __syncthreads();

    const int wv = threadIdx.x >> 6;
    const int ln = threadIdx.x & 63;
    const int m  = blockIdx.x * 4 + wv;
    const float4 V  = vox4[m];
    const float2 RC = rot2[m];

    // ---- phase 1: ordered ballot scan ----
    int cnt = 0;
    for (int it = 0; it < 16; it++) {
        const float4 p = dl4[it * 64 + ln];
        const float d2 = p.w + V.w - 2.f * (p.x * V.x + p.y * V.y + p.z * V.z);
        const unsigned long long mask = __ballot(d2 <= VOX_R2);
        if (mask) {
            const int pop  = __popcll(mask);
            const int need = NSAMP - cnt;
            const int pre  = __popcll(mask & ((1ull << ln) - 1ull));
            if ((d2 <= VOX_R2) && pre < need) lists[wv][cnt + pre] = it * 64 + ln;
            cnt += min(pop, need);
            if (cnt >= NSAMP) break;
        }
    }
    __syncthreads();   // lists visible (cross-lane LDS RAW), cheap

    // ---- phase 2: features ----
    const int K  = cnt;          // wave-uniform
    const int ch = ln & 15;
    const int sg = ln >> 4;      // sample subgroup 0..3
    const float wr0 = w_raise[ch * 3 + 0];
    const float wr1 = w_raise[ch * 3 + 1];
    const float wr2 = w_raise[ch * 3 + 2];
    const float br  = b_raise[ch];

    float mx = -1e30f, mn = 1e30f, sm = 0.f, sq = 0.f;
    for (int s0 = 0; s0 < K; s0 += 4) {
        const int s = s0 + sg;
        if (s < K) {
            const float4 p = dl4[lists[wv][s]];
            const float rx = p.x - V.x, ry = p.y - V.y, rz = p.z - V.z;
            const float ox =  rx * RC.x + ry * RC.y;
            const float oy = -rx * RC.y + ry * RC.x;
            const float x  = wr0 * ox + wr1 * oy + wr2 * rz + br;
            mx = fmaxf(mx, x); mn = fminf(mn, x);
            sm += x; sq += x * x;
        }
    }
    const int rem = NSAMP - K;
    if (sg == 0 && rem > 0) {    // padding samples contribute x = br
        mx = fmaxf(mx, br); mn = fminf(mn, br);
        sm += (float)rem * br; sq += (float)rem * br * br;
    }
    // reduce across the 4 subgroups (xor 16, 32)
    mx = fmaxf(mx, __shfl_xor(mx, 16)); mx = fmaxf(mx, __shfl_xor(mx, 32));
    mn = fminf(mn, __shfl_xor(mn, 16)); mn = fminf(mn, __shfl_xor(mn, 32));
    sm += __shfl_xor(sm, 16); sm += __shfl_xor(sm, 32);
    sq += __shfl_xor(sq, 16); sq += __shfl_xor(sq, 32);

    if (ln < 16) {
        const size_t o = ((size_t)b * 16 + ch) * M_TOT + m;
        xmax[o] = mx; xmin[o] = mn; xsum[o] = sm; xsq[o] = sq;
    }
}

// ---------------------------------------------------------------------------
// Kernel 1b: reduce xsum/xsq -> stats[ch], stats[32+ch]. grid=(16,2,8)
__global__ __launch_bounds__(256)
void k_nstats(const float* __restrict__ xsum, const float* __restrict__ xsq,
              float* __restrict__ stats)
{
    const int ch    = blockIdx.x;
    const int isq   = blockIdx.y;
    const int chunk = blockIdx.z;
    const float* src = isq ? xsq : xsum;
    const int per = M_TOT / 8;
    float s = 0.f;
    for (int b = 0; b < BATCH; b++) {
        const float* p = src + ((size_t)b * 16 + ch) * M_TOT + chunk * per;
        for (int i = threadIdx.x; i < per; i += 256) s += p[i];
    }
    for (int off = 32; off; off >>= 1) s += __shfl_xor(s, off);
    __shared__ float red[4];
    if ((threadIdx.x & 63) == 0) red[threadIdx.x >> 6] = s;
    __syncthreads();
    if (threadIdx.x == 0)
        atomicAdd(&stats[isq * 32 + ch], red[0] + red[1] + red[2] + red[3]);
}

// ---------------------------------------------------------------------------
// Kernel 2: BN0 affine + relu applied to the max/min -> act0 (B,16,9,40,80)
__global__ __launch_bounds__(256)
void k_bn0(const float* __restrict__ xmax, const float* __restrict__ xmin,
           float* __restrict__ act,
           const float* __restrict__ stats,
           const float* __restrict__ g, const float* __restrict__ be)
{
    const int idx = blockIdx.x * 256 + threadIdx.x;
    const int total = BATCH * 16 * M_TOT;
    if (idx >= total) return;
    const int ch = (idx / M_TOT) & 15;
    const float cnt = (float)((size_t)BATCH * M_TOT * NSAMP);
    const float mean = stats[ch] / cnt;
    const float var  = stats[32 + ch] / cnt - mean * mean;
    const float sc = g[ch] * rsqrtf(var + EPSBN);
    const float sh = be[ch] - mean * sc;
    const float v = (sc >= 0.f) ? xmax[idx] : xmin[idx];
    const float r = sc * v + sh;
    act[idx] = r > 0.f ? r : 0.f;
}

// ---------------------------------------------------------------------------
// Conv 3x3x3, H zero-pad, W wrap, D valid. NCO=8 channels per thread,
// weights via wave-uniform (SGPR) addresses. block=320, grid=(10,DOUT,B*4)
template <int CIN, int DOUT>
__global__ __launch_bounds__(320)
void k_conv(const float* __restrict__ xin, const float* __restrict__ wgt,
            const float* __restrict__ bias,
            float* __restrict__ y, float* __restrict__ stats)
{
    constexpr int DIN = DOUT + 2;
    const int cog = blockIdx.z & 3;
    const int b   = blockIdx.z >> 2;
    const int d   = blockIdx.y;
    const int h   = blockIdx.x * 4 + threadIdx.x / 80;
    const int w   = threadIdx.x % 80;
    const int wm1 = (w == 0) ? 79 : w - 1;
    const int wp1 = (w == 79) ? 0 : w + 1;

    float acc[8];
#pragma unroll
    for (int c = 0; c < 8; c++) acc[c] = bias[cog * 8 + c];

    const float* xb = xin + (size_t)b * CIN * DIN * 3200 + (size_t)d * 3200;
    const float* wb = wgt + (size_t)(cog * 8) * CIN * 27;

#pragma unroll 1
    for (int ci = 0; ci < CIN; ci++) {
        const float* xc  = xb + (size_t)ci * DIN * 3200;
        const float* wc  = wb + ci * 27;
#pragma unroll
        for (int kd = 0; kd < 3; kd++) {
            const float* xd = xc + kd * 3200;
#pragma unroll
            for (int kh = 0; kh < 3; kh++) {
                const int hh = h + kh - 1;
                if (hh < 0 || hh >= ELE_N) continue;
                const float* xr = xd + hh * 80;
                const float x0 = xr[wm1];
                const float x1 = xr[w];
                const float x2 = xr[wp1];
                const float* wk = wc + kd * 9 + kh * 3;
#pragma unroll
                for (int c = 0; c < 8; c++) {
                    const float* wcc = wk + c * (CIN * 27);
                    acc[c] = fmaf(x2, wcc[2], fmaf(x1, wcc[1], fmaf(x0, wcc[0], acc[c])));
                }
            }
        }
    }

#pragma unroll
    for (int c = 0; c < 8; c++) {
        y[(((size_t)b * 32 + cog * 8 + c) * DOUT + d) * 3200 + h * 80 + w] = acc[c];
    }

    __shared__ float red[5][16];
    const int wv = threadIdx.x >> 6;
    const int ln = threadIdx.x & 63;
#pragma unroll
    for (int c = 0; c < 8; c++) {
        float s = acc[c], q = acc[c] * acc[c];
        for (int off = 32; off; off >>= 1) {
            s += __shfl_xor(s, off);
            q += __shfl_xor(q, off);
        }
        if (ln == 0) { red[wv][c] = s; red[wv][8 + c] = q; }
    }
    __syncthreads();
    if (threadIdx.x < 16) {
        const float v = red[0][threadIdx.x] + red[1][threadIdx.x] + red[2][threadIdx.x] +
                        red[3][threadIdx.x] + red[4][threadIdx.x];
        const int c   = threadIdx.x & 7;
        const int isq = threadIdx.x >> 3;
        atomicAdd(&stats[isq * 32 + cog * 8 + c], v);
    }
}

// ---------------------------------------------------------------------------
// BN + relu on a conv raw output (32 channels), layout (B,32,dhw)
__global__ __launch_bounds__(256)
void k_bnrelu(const float* __restrict__ y, float* __restrict__ act,
              const float* __restrict__ stats,
              const float* __restrict__ g, const float* __restrict__ be,
              float per_ch_count, int dhw, int total)
{
    const int idx = blockIdx.x * 256 + threadIdx.x;
    if (idx >= total) return;
    const int ch = (idx / dhw) & 31;
    const float mean = stats[ch] / per_ch_count;
    const float var  = stats[32 + ch] / per_ch_count - mean * mean;
    const float sc = g[ch] * rsqrtf(var + EPSBN);
    const float sh = be[ch] - mean * sc;
    const float r = sc * y[idx] + sh;
    act[idx] = r > 0.f ? r : 0.f;
}

// ---------------------------------------------------------------------------
// Final: max over H,W of relu(bn(y4)), y4 (B,32,1,40,80). grid=64 blocks
__global__ __launch_bounds__(256)
void k_final(const float* __restrict__ y4,
             const float* __restrict__ stats,
             const float* __restrict__ g, const float* __restrict__ be,
             float* __restrict__ out)
{
    const int b = blockIdx.x >> 5;
    const int co = blockIdx.x & 31;
    const float* src = y4 + ((size_t)b * 32 + co) * 3200;
    float mx = -1e30f, mn = 1e30f;
    for (int i = threadIdx.x; i < 3200; i += 256) {
        const float v = src[i];
        mx = fmaxf(mx, v);
        mn = fminf(mn, v);
    }
    for (int off = 32; off; off >>= 1) {
        mx = fmaxf(mx, __shfl_xor(mx, off));
        mn = fminf(mn, __shfl_xor(mn, off));
    }
    __shared__ float rmx[4], rmn[4];
    const int wv = threadIdx.x >> 6;
    if ((threadIdx.x & 63) == 0) { rmx[wv] = mx; rmn[wv] = mn; }
    __syncthreads();
    if (threadIdx.x == 0) {
        float MX = rmx[0], MN = rmn[0];
#pragma unroll
        for (int i = 1; i < 4; i++) { MX = fmaxf(MX, rmx[i]); MN = fminf(MN, rmn[i]); }
        const float cnt = (float)(BATCH * 1 * 3200);
        const float mean = stats[co] / cnt;
        const float var  = stats[32 + co] / cnt - mean * mean;
        const float sc = g[co] * rsqrtf(var + EPSBN);
        const float sh = be[co] - mean * sc;
        const float v = (sc >= 0.f) ? MX : MN;
        const float r = sc * v + sh;
        out[b * 32 + co] = r > 0.f ? r : 0.f;
    }
}

// ---------------------------------------------------------------------------
extern "C" void kernel_launch(void* const* d_in, const int* in_sizes, int n_in,
                              void* d_out, int out_size, void* d_ws, size_t ws_size,
                              hipStream_t stream)
{
    const float* pts     = (const float*)d_in[0];
    const float* w_raise = (const float*)d_in[1];
    const float* b_raise = (const float*)d_in[2];
    const float* g0      = (const float*)d_in[3];
    const float* be0     = (const float*)d_in[4];
    const float* w1  = (const float*)d_in[5];
    const float* b1  = (const float*)d_in[6];
    const float* g1  = (const float*)d_in[7];
    const float* be1 = (const float*)d_in[8];
    const float* w2  = (const float*)d_in[9];
    const float* b2  = (const float*)d_in[10];
    const float* g2  = (const float*)d_in[11];
    const float* be2 = (const float*)d_in[12];
    const float* w3  = (const float*)d_in[13];
    const float* b3  = (const float*)d_in[14];
    const float* g3  = (const float*)d_in[15];
    const float* be3 = (const float*)d_in[16];
    const float* w4  = (const float*)d_in[17];
    const float* b4  = (const float*)d_in[18];
    const float* g4  = (const float*)d_in[19];
    const float* be4 = (const float*)d_in[20];
    float* out = (float*)d_out;

    // workspace layout (float offsets):
    //   stats  @ 0        (512)   zeroed each call
    //   vox4   @ 512      (115200 = 28800*float4), 16B-aligned
    //   rot2   @ 115712   (57600)
    //   xmax   @ 173312   (921600)   -- later Y (conv raw, needs 1433600 <= xmax+xmin)
    //   xmin   @ 1094912  (921600)
    //   xsum   @ 2016512  (921600)   -- later A (activated, needs 1433600 <= xsum+xsq)
    //   xsq    @ 2938112  (921600)
    //   act0   @ 3859712  (921600)
    //   total 4781312 floats = 18.3 MB
    float* wsf   = (float*)d_ws;
    float*  stats = wsf;
    float4* vox4  = (float4*)(wsf + 512);
    float2* rot2  = (float2*)(wsf + 115712);
    float*  xmax  = wsf + 173312;
    float*  xmin  = wsf + 1094912;
    float*  xsum  = wsf + 2016512;
    float*  xsq   = wsf + 2938112;
    float*  act0  = wsf + 3859712;
    float*  Y = xmax;   // conv raw output ping
    float*  A = xsum;   // activated pong

    hipMemsetAsync(stats, 0, 512 * sizeof(float), stream);

    k_vox<<<(M_TOT + 255) / 256, 256, 0, stream>>>(vox4, rot2);

    k_neighbor<<<dim3(M_TOT / 4, BATCH), 256, 0, stream>>>(
        pts, vox4, rot2, w_raise, b_raise, xmax, xmin, xsum, xsq);

    k_nstats<<<dim3(16, 2, 8), 256, 0, stream>>>(xsum, xsq, stats);

    {
        const int total = BATCH * 16 * M_TOT;
        k_bn0<<<(total + 255) / 256, 256, 0, stream>>>(xmax, xmin, act0, stats, g0, be0);
    }

    // layer1: act0 (B,16,9,...) -> Y (B,32,7,...)
    k_conv<16, 7><<<dim3(10, 7, BATCH * 4), 320, 0, stream>>>(act0, w1, b1, Y, stats + 64);
    k_bnrelu<<<(BATCH * 32 * 7 * 3200 + 255) / 256, 256, 0, stream>>>(
        Y, A, stats + 64, g1, be1, (float)(BATCH * 7 * 3200), 7 * 3200, BATCH * 32 * 7 * 3200);

    // layer2: A (B,32,7) -> Y (B,32,5)
    k_conv<32, 5><<<dim3(10, 5, BATCH * 4), 320, 0, stream>>>(A, w2, b2, Y, stats + 128);
    k_bnrelu<<<(BATCH * 32 * 5 * 3200 + 255) / 256, 256, 0, stream>>>(
        Y, A, stats + 128, g2, be2, (float)(BATCH * 5 * 3200), 5 * 3200, BATCH * 32 * 5 * 3200);

    // layer3: A (B,32,5) -> Y (B,32,3)
    k_conv<32, 3><<<dim3(10, 3, BATCH * 4), 320, 0, stream>>>(A, w3, b3, Y, stats + 192);
    k_bnrelu<<<(BATCH * 32 * 3 * 3200 + 255) / 256, 256, 0, stream>>>(
        Y, A, stats + 192, g3, be3, (float)(BATCH * 3 * 3200), 3 * 3200, BATCH * 32 * 3 * 3200);

    // layer4: A (B,32,3) -> Y (B,32,1)
    k_conv<32, 1><<<dim3(10, 1, BATCH * 4), 320, 0, stream>>>(A, w4, b4, Y, stats + 256);

    k_final<<<BATCH * 32, 256, 0, stream>>>(Y, stats + 256, g4, be4, out);
}

// Round 6
// 357.711 us; speedup vs baseline: 2.2979x; 1.3787x over previous
//
#include <hip/hip_runtime.h>
#include <math.h>

#define RAD_N 9
#define ELE_N 40
#define AZI_N 80
#define M_TOT 28800          // RAD_N*ELE_N*AZI_N
#define NPTS 1024
#define NSAMP 30
#define BATCH 2
#define VOX_R2 0.09f
#define EPSBN 1e-5f

// ---------------------------------------------------------------------------
// Kernel 0: voxel-center precompute (double precision to match numpy f64->f32)
__global__ __launch_bounds__(256)
void k_vox(float4* __restrict__ vox4, float2* __restrict__ rot2)
{
    const int m = blockIdx.x * 256 + threadIdx.x;
    if (m >= M_TOT) return;
    const int ri = m / (ELE_N * AZI_N);
    const int rm = m - ri * (ELE_N * AZI_N);
    const int ei = rm / AZI_N;
    const int ai = rm - ei * AZI_N;
    const double rd = (ri + 0.5) * (2.0 / (double)RAD_N);
    const double ed = (ei + 0.5) * (M_PI / (double)ELE_N);
    const double ad = (ai + 0.5) * (2.0 * M_PI / (double)AZI_N);
    const float vx = (float)(rd * sin(ed) * cos(ad));
    const float vy = (float)(rd * sin(ed) * sin(ad));
    const float vz = (float)(rd * cos(ed));
    vox4[m] = make_float4(vx, vy, vz, vx * vx + vy * vy + vz * vz);
    const float ang = -((float)ai * (float)(2.0 * M_PI / (double)AZI_N));
    rot2[m] = make_float2(cosf(ang), sinf(ang));
}

// ---------------------------------------------------------------------------
// Kernel 1: wave-per-voxel ballot neighbor scan + raise-to-16ch features.
__global__ __launch_bounds__(256)
void k_neighbor(const float* __restrict__ pts,
                const float4* __restrict__ vox4,
                const float2* __restrict__ rot2,
                const float* __restrict__ w_raise,
                const float* __restrict__ b_raise,
                float* __restrict__ xmax, float* __restrict__ xmin,
                float* __restrict__ xsum, float* __restrict__ xsq)
{
    __shared__ float4 dl4[NPTS];
    __shared__ int lists[4][NSAMP];
    const int b = blockIdx.y;
    const float* P = pts + (size_t)b * NPTS * 3;
    const float cx = P[(NPTS - 1) * 3 + 0];
    const float cy = P[(NPTS - 1) * 3 + 1];
    const float cz = P[(NPTS - 1) * 3 + 2];
    for (int n = threadIdx.x; n < NPTS; n += 256) {
        const float dx = P[n * 3 + 0] - cx;
        const float dy = P[n * 3 + 1] - cy;
        const float dz = P[n * 3 + 2] - cz;
        dl4[n] = make_float4(dx, dy, dz, dx * dx + dy * dy + dz * dz);
    }
    __syncthreads();

    const int wv = threadIdx.x >> 6;
    const int ln = threadIdx.x & 63;
    const int m  = blockIdx.x * 4 + wv;
    const float4 V  = vox4[m];
    const float2 RC = rot2[m];

    // ---- phase 1: ordered ballot scan ----
    int cnt = 0;
    for (int it = 0; it < 16; it++) {
        const float4 p = dl4[it * 64 + ln];
        const float d2 = p.w + V.w - 2.f * (p.x * V.x + p.y * V.y + p.z * V.z);
        const unsigned long long mask = __ballot(d2 <= VOX_R2);
        if (mask) {
            const int pop  = __popcll(mask);
            const int need = NSAMP - cnt;
            const int pre  = __popcll(mask & ((1ull << ln) - 1ull));
            if ((d2 <= VOX_R2) && pre < need) lists[wv][cnt + pre] = it * 64 + ln;
            cnt += min(pop, need);
            if (cnt >= NSAMP) break;
        }
    }
    __syncthreads();

    // ---- phase 2: features ----
    const int K  = cnt;
    const int ch = ln & 15;
    const int sg = ln >> 4;
    const float wr0 = w_raise[ch * 3 + 0];
    const float wr1 = w_raise[ch * 3 + 1];
    const float wr2 = w_raise[ch * 3 + 2];
    const float br  = b_raise[ch];

    float mx = -1e30f, mn = 1e30f, sm = 0.f, sq = 0.f;
    for (int s0 = 0; s0 < K; s0 += 4) {
        const int s = s0 + sg;
        if (s < K) {
            const float4 p = dl4[lists[wv][s]];
            const float rx = p.x - V.x, ry = p.y - V.y, rz = p.z - V.z;
            const float ox =  rx * RC.x + ry * RC.y;
            const float oy = -rx * RC.y + ry * RC.x;
            const float x  = wr0 * ox + wr1 * oy + wr2 * rz + br;
            mx = fmaxf(mx, x); mn = fminf(mn, x);
            sm += x; sq += x * x;
        }
    }
    const int rem = NSAMP - K;
    if (sg == 0 && rem > 0) {
        mx = fmaxf(mx, br); mn = fminf(mn, br);
        sm += (float)rem * br; sq += (float)rem * br * br;
    }
    mx = fmaxf(mx, __shfl_xor(mx, 16)); mx = fmaxf(mx, __shfl_xor(mx, 32));
    mn = fminf(mn, __shfl_xor(mn, 16)); mn = fminf(mn, __shfl_xor(mn, 32));
    sm += __shfl_xor(sm, 16); sm += __shfl_xor(sm, 32);
    sq += __shfl_xor(sq, 16); sq += __shfl_xor(sq, 32);

    if (ln < 16) {
        const size_t o = ((size_t)b * 16 + ch) * M_TOT + m;
        xmax[o] = mx; xmin[o] = mn; xsum[o] = sm; xsq[o] = sq;
    }
}

// ---------------------------------------------------------------------------
// Kernel 1b: reduce xsum/xsq -> stats[ch], stats[32+ch]. grid=(16,2,8)
__global__ __launch_bounds__(256)
void k_nstats(const float* __restrict__ xsum, const float* __restrict__ xsq,
              float* __restrict__ stats)
{
    const int ch    = blockIdx.x;
    const int isq   = blockIdx.y;
    const int chunk = blockIdx.z;
    const float* src = isq ? xsq : xsum;
    const int per = M_TOT / 8;
    float s = 0.f;
    for (int b = 0; b < BATCH; b++) {
        const float* p = src + ((size_t)b * 16 + ch) * M_TOT + chunk * per;
        for (int i = threadIdx.x; i < per; i += 256) s += p[i];
    }
    for (int off = 32; off; off >>= 1) s += __shfl_xor(s, off);
    __shared__ float red[4];
    if ((threadIdx.x & 63) == 0) red[threadIdx.x >> 6] = s;
    __syncthreads();
    if (threadIdx.x == 0)
        atomicAdd(&stats[isq * 32 + ch], red[0] + red[1] + red[2] + red[3]);
}

// ---------------------------------------------------------------------------
// Kernel 2: BN0 affine + relu applied to the max/min -> act0 (B,16,9,40,80)
__global__ __launch_bounds__(256)
void k_bn0(const float* __restrict__ xmax, const float* __restrict__ xmin,
           float* __restrict__ act,
           const float* __restrict__ stats,
           const float* __restrict__ g, const float* __restrict__ be)
{
    const int idx = blockIdx.x * 256 + threadIdx.x;
    const int total = BATCH * 16 * M_TOT;
    if (idx >= total) return;
    const int ch = (idx / M_TOT) & 15;
    const float cnt = (float)((size_t)BATCH * M_TOT * NSAMP);
    const float mean = stats[ch] / cnt;
    const float var  = stats[32 + ch] / cnt - mean * mean;
    const float sc = g[ch] * rsqrtf(var + EPSBN);
    const float sh = be[ch] - mean * sc;
    const float v = (sc >= 0.f) ? xmax[idx] : xmin[idx];
    const float r = sc * v + sh;
    act[idx] = r > 0.f ? r : 0.f;
}

// ---------------------------------------------------------------------------
// Conv 3x3x3, H zero-pad, W wrap, D valid. NCO=8 channels per thread, the ci
// reduction split across CIN/CICHUNK blocks that atomicAdd partial sums into
// pre-zeroed y (chunk 0 seeds the bias). block=320,
// grid = (10, DOUT, B * (CIN/CICHUNK) * 4)
template <int CIN, int DOUT, int CICHUNK>
__global__ __launch_bounds__(320)
void k_conv(const float* __restrict__ xin, const float* __restrict__ wgt,
            const float* __restrict__ bias,
            float* __restrict__ y)
{
    constexpr int DIN = DOUT + 2;
    constexpr int NCHUNK = CIN / CICHUNK;
    const int cog   = blockIdx.z & 3;
    const int chunk = (blockIdx.z >> 2) % NCHUNK;
    const int b     = blockIdx.z / (4 * NCHUNK);
    const int d     = blockIdx.y;
    const int h     = blockIdx.x * 4 + threadIdx.x / 80;
    const int w     = threadIdx.x % 80;
    const int wm1   = (w == 0) ? 79 : w - 1;
    const int wp1   = (w == 79) ? 0 : w + 1;

    float acc[8];
#pragma unroll
    for (int c = 0; c < 8; c++) acc[c] = (chunk == 0) ? bias[cog * 8 + c] : 0.f;

    const float* xb = xin + (size_t)b * CIN * DIN * 3200
                          + (size_t)(chunk * CICHUNK) * DIN * 3200 + (size_t)d * 3200;
    const float* wb = wgt + (size_t)(cog * 8) * CIN * 27 + chunk * CICHUNK * 27;

#pragma unroll 1
    for (int ci = 0; ci < CICHUNK; ci++) {
        const float* xc  = xb + (size_t)ci * DIN * 3200;
        const float* wc  = wb + ci * 27;
#pragma unroll
        for (int kd = 0; kd < 3; kd++) {
            const float* xd = xc + kd * 3200;
#pragma unroll
            for (int kh = 0; kh < 3; kh++) {
                const int hh = h + kh - 1;
                if (hh < 0 || hh >= ELE_N) continue;
                const float* xr = xd + hh * 80;
                const float x0 = xr[wm1];
                const float x1 = xr[w];
                const float x2 = xr[wp1];
                const float* wk = wc + kd * 9 + kh * 3;
#pragma unroll
                for (int c = 0; c < 8; c++) {
                    const float* wcc = wk + c * (CIN * 27);
                    acc[c] = fmaf(x2, wcc[2], fmaf(x1, wcc[1], fmaf(x0, wcc[0], acc[c])));
                }
            }
        }
    }

#pragma unroll
    for (int c = 0; c < 8; c++) {
        atomicAdd(&y[(((size_t)b * 32 + cog * 8 + c) * DOUT + d) * 3200 + h * 80 + w],
                  acc[c]);
    }
}

// ---------------------------------------------------------------------------
// Per-co sum/sumsq over conv output y (B,32,dhw) -> stats[co], stats[32+co]
// grid = (32, 8), block = 256
__global__ __launch_bounds__(256)
void k_ystats(const float* __restrict__ y, float* __restrict__ stats, int dhw)
{
    const int co  = blockIdx.x;
    const int per = dhw >> 3;
    const int i0  = blockIdx.y * per;
    float s = 0.f, q = 0.f;
    for (int b = 0; b < BATCH; b++) {
        const float* p = y + ((size_t)b * 32 + co) * dhw + i0;
        for (int i = threadIdx.x; i < per; i += 256) {
            const float v = p[i];
            s += v; q += v * v;
        }
    }
    for (int off = 32; off; off >>= 1) {
        s += __shfl_xor(s, off);
        q += __shfl_xor(q, off);
    }
    __shared__ float red[4][2];
    if ((threadIdx.x & 63) == 0) { red[threadIdx.x >> 6][0] = s; red[threadIdx.x >> 6][1] = q; }
    __syncthreads();
    if (threadIdx.x == 0) {
        float S = 0.f, Q = 0.f;
#pragma unroll
        for (int i = 0; i < 4; i++) { S += red[i][0]; Q += red[i][1]; }
        atomicAdd(&stats[co], S);
        atomicAdd(&stats[32 + co], Q);
    }
}

// ---------------------------------------------------------------------------
// BN + relu on a conv raw output (32 channels), layout (B,32,dhw)
__global__ __launch_bounds__(256)
void k_bnrelu(const float* __restrict__ y, float* __restrict__ act,
              const float* __restrict__ stats,
              const float* __restrict__ g, const float* __restrict__ be,
              float per_ch_count, int dhw, int total)
{
    const int idx = blockIdx.x * 256 + threadIdx.x;
    if (idx >= total) return;
    const int ch = (idx / dhw) & 31;
    const float mean = stats[ch] / per_ch_count;
    const float var  = stats[32 + ch] / per_ch_count - mean * mean;
    const float sc = g[ch] * rsqrtf(var + EPSBN);
    const float sh = be[ch] - mean * sc;
    const float r = sc * y[idx] + sh;
    act[idx] = r > 0.f ? r : 0.f;
}

// ---------------------------------------------------------------------------
// Final: max over H,W of relu(bn(y4)), y4 (B,32,1,40,80). grid=64 blocks
__global__ __launch_bounds__(256)
void k_final(const float* __restrict__ y4,
             const float* __restrict__ stats,
             const float* __restrict__ g, const float* __restrict__ be,
             float* __restrict__ out)
{
    const int b = blockIdx.x >> 5;
    const int co = blockIdx.x & 31;
    const float* src = y4 + ((size_t)b * 32 + co) * 3200;
    float mx = -1e30f, mn = 1e30f;
    for (int i = threadIdx.x; i < 3200; i += 256) {
        const float v = src[i];
        mx = fmaxf(mx, v);
        mn = fminf(mn, v);
    }
    for (int off = 32; off; off >>= 1) {
        mx = fmaxf(mx, __shfl_xor(mx, off));
        mn = fminf(mn, __shfl_xor(mn, off));
    }
    __shared__ float rmx[4], rmn[4];
    const int wv = threadIdx.x >> 6;
    if ((threadIdx.x & 63) == 0) { rmx[wv] = mx; rmn[wv] = mn; }
    __syncthreads();
    if (threadIdx.x == 0) {
        float MX = rmx[0], MN = rmn[0];
#pragma unroll
        for (int i = 1; i < 4; i++) { MX = fmaxf(MX, rmx[i]); MN = fminf(MN, rmn[i]); }
        const float cnt = (float)(BATCH * 1 * 3200);
        const float mean = stats[co] / cnt;
        const float var  = stats[32 + co] / cnt - mean * mean;
        const float sc = g[co] * rsqrtf(var + EPSBN);
        const float sh = be[co] - mean * sc;
        const float v = (sc >= 0.f) ? MX : MN;
        const float r = sc * v + sh;
        out[b * 32 + co] = r > 0.f ? r : 0.f;
    }
}

// ---------------------------------------------------------------------------
extern "C" void kernel_launch(void* const* d_in, const int* in_sizes, int n_in,
                              void* d_out, int out_size, void* d_ws, size_t ws_size,
                              hipStream_t stream)
{
    const float* pts     = (const float*)d_in[0];
    const float* w_raise = (const float*)d_in[1];
    const float* b_raise = (const float*)d_in[2];
    const float* g0      = (const float*)d_in[3];
    const float* be0     = (const float*)d_in[4];
    const float* w1  = (const float*)d_in[5];
    const float* b1  = (const float*)d_in[6];
    const float* g1  = (const float*)d_in[7];
    const float* be1 = (const float*)d_in[8];
    const float* w2  = (const float*)d_in[9];
    const float* b2  = (const float*)d_in[10];
    const float* g2  = (const float*)d_in[11];
    const float* be2 = (const float*)d_in[12];
    const float* w3  = (const float*)d_in[13];
    const float* b3  = (const float*)d_in[14];
    const float* g3  = (const float*)d_in[15];
    const float* be3 = (const float*)d_in[16];
    const float* w4  = (const float*)d_in[17];
    const float* b4  = (const float*)d_in[18];
    const float* g4  = (const float*)d_in[19];
    const float* be4 = (const float*)d_in[20];
    float* out = (float*)d_out;

    // workspace layout (float offsets):
    //   stats @ 0 (512; [0]=bn0, +64=l1, +128=l2, +192=l3, +256=l4)
    //   vox4  @ 512 (115200), rot2 @ 115712 (57600)
    //   poolA @ 173312 (3686400): first xmax/xmin/xsum/xsq, then (after bn0)
    //          re-used as contiguous conv outputs Y1..Y4 (3276800, memset to 0)
    //   act0  @ 3859712 (921600)
    //   A     @ 4781312 (1433600)  activated ping-pong
    //   total 6214912 floats = 23.7 MB
    float* wsf   = (float*)d_ws;
    float*  stats = wsf;
    float4* vox4  = (float4*)(wsf + 512);
    float2* rot2  = (float2*)(wsf + 115712);
    float*  xmax  = wsf + 173312;
    float*  xmin  = wsf + 1094912;
    float*  xsum  = wsf + 2016512;
    float*  xsq   = wsf + 2938112;
    float*  act0  = wsf + 3859712;
    float*  A     = wsf + 4781312;
    float*  Y1 = wsf + 173312;                    // 1,433,600 (B*32*7*3200)
    float*  Y2 = Y1 + 1433600;                    // 1,024,000
    float*  Y3 = Y2 + 1024000;                    //   614,400
    float*  Y4 = Y3 + 614400;                     //   204,800

    hipMemsetAsync(stats, 0, 512 * sizeof(float), stream);

    k_vox<<<(M_TOT + 255) / 256, 256, 0, stream>>>(vox4, rot2);

    k_neighbor<<<dim3(M_TOT / 4, BATCH), 256, 0, stream>>>(
        pts, vox4, rot2, w_raise, b_raise, xmax, xmin, xsum, xsq);

    k_nstats<<<dim3(16, 2, 8), 256, 0, stream>>>(xsum, xsq, stats);

    k_bn0<<<(BATCH * 16 * M_TOT + 255) / 256, 256, 0, stream>>>(
        xmax, xmin, act0, stats, g0, be0);

    // zero Y1..Y4 (contiguous) for atomic accumulation; poolA is dead now
    hipMemsetAsync(Y1, 0, 3276800 * sizeof(float), stream);

    // layer1: act0 (B,16,9) -> Y1 (B,32,7); ci-split 16/4 -> z = 2*4*4
    k_conv<16, 7, 4><<<dim3(10, 7, 32), 320, 0, stream>>>(act0, w1, b1, Y1);
    k_ystats<<<dim3(32, 8), 256, 0, stream>>>(Y1, stats + 64, 7 * 3200);
    k_bnrelu<<<(BATCH * 32 * 7 * 3200 + 255) / 256, 256, 0, stream>>>(
        Y1, A, stats + 64, g1, be1, (float)(BATCH * 7 * 3200), 7 * 3200, BATCH * 32 * 7 * 3200);

    // layer2: A (B,32,7) -> Y2 (B,32,5); ci-split 32/8 -> z = 2*4*4
    k_conv<32, 5, 8><<<dim3(10, 5, 32), 320, 0, stream>>>(A, w2, b2, Y2);
    k_ystats<<<dim3(32, 8), 256, 0, stream>>>(Y2, stats + 128, 5 * 3200);
    k_bnrelu<<<(BATCH * 32 * 5 * 3200 + 255) / 256, 256, 0, stream>>>(
        Y2, A, stats + 128, g2, be2, (float)(BATCH * 5 * 3200), 5 * 3200, BATCH * 32 * 5 * 3200);

    // layer3: A (B,32,5) -> Y3 (B,32,3); ci-split 32/8 -> z = 2*4*4
    k_conv<32, 3, 8><<<dim3(10, 3, 32), 320, 0, stream>>>(A, w3, b3, Y3);
    k_ystats<<<dim3(32, 8), 256, 0, stream>>>(Y3, stats + 192, 3 * 3200);
    k_bnrelu<<<(BATCH * 32 * 3 * 3200 + 255) / 256, 256, 0, stream>>>(
        Y3, A, stats + 192, g3, be3, (float)(BATCH * 3 * 3200), 3 * 3200, BATCH * 32 * 3 * 3200);

    // layer4: A (B,32,3) -> Y4 (B,32,1); ci-split 32/4 -> z = 2*8*4
    k_conv<32, 1, 4><<<dim3(10, 1, 64), 320, 0, stream>>>(A, w4, b4, Y4);
    k_ystats<<<dim3(32, 8), 256, 0, stream>>>(Y4, stats + 256, 3200);

    k_final<<<BATCH * 32, 256, 0, stream>>>(Y4, stats + 256, g4, be4, out);
}